// Round 1
// baseline (998.140 us; speedup 1.0000x reference)
//
#include <hip/hip_runtime.h>
#include <math.h>

#define D_MODEL 1024
#define D_INT   64
#define KW      32
#define B_SZ    2
#define L_SEQ   4096
#define SUBHEADS 5
#define HEADS   14
#define M_ROWS  (B_SZ * L_SEQ)   // 8192
#define N_CAT   (HEADS * D_INT)  // 896

// ---------------------------------------------------------------------------
// Projection GEMM: out[h][m][i] = sum_d X[m][d] * W[h][d][i] + bias[h][i]
// X: [M_ROWS, D_MODEL], W: [heads][D_MODEL][64], out: [heads][M_ROWS][64]
// grid: (M_ROWS/64, heads), block: 256
// ---------------------------------------------------------------------------
__global__ __launch_bounds__(256)
void proj_gemm(const float* __restrict__ X, const float* __restrict__ W,
               const float* __restrict__ bias, float* __restrict__ out)
{
    __shared__ float As[16][64];
    __shared__ float Bs[16][64];
    const int h    = blockIdx.y;
    const int row0 = blockIdx.x * 64;
    const int tid  = threadIdx.x;
    const int tx   = tid & 15;       // n / 4
    const int ty   = tid >> 4;       // m / 4
    const float* Wh = W + (long)h * D_MODEL * 64;

    const int am = tid >> 2;         // 0..63 : A row within tile
    const int ak = (tid & 3) * 4;    // 0,4,8,12 : A k within tile
    const int bk = tid >> 4;         // 0..15 : B k within tile
    const int bn = (tid & 15) * 4;   // B n within tile

    float acc[4][4] = {};

    for (int k0 = 0; k0 < D_MODEL; k0 += 16) {
        float4 av = *(const float4*)&X[(long)(row0 + am) * D_MODEL + k0 + ak];
        float4 bv = *(const float4*)&Wh[(long)(k0 + bk) * 64 + bn];
        __syncthreads();
        As[ak + 0][am] = av.x; As[ak + 1][am] = av.y;
        As[ak + 2][am] = av.z; As[ak + 3][am] = av.w;
        *(float4*)&Bs[bk][bn] = bv;
        __syncthreads();
#pragma unroll
        for (int kk = 0; kk < 16; kk++) {
            float a0 = As[kk][ty * 4 + 0], a1 = As[kk][ty * 4 + 1];
            float a2 = As[kk][ty * 4 + 2], a3 = As[kk][ty * 4 + 3];
            float b0 = Bs[kk][tx * 4 + 0], b1 = Bs[kk][tx * 4 + 1];
            float b2 = Bs[kk][tx * 4 + 2], b3 = Bs[kk][tx * 4 + 3];
            acc[0][0] += a0 * b0; acc[0][1] += a0 * b1; acc[0][2] += a0 * b2; acc[0][3] += a0 * b3;
            acc[1][0] += a1 * b0; acc[1][1] += a1 * b1; acc[1][2] += a1 * b2; acc[1][3] += a1 * b3;
            acc[2][0] += a2 * b0; acc[2][1] += a2 * b1; acc[2][2] += a2 * b2; acc[2][3] += a2 * b3;
            acc[3][0] += a3 * b0; acc[3][1] += a3 * b1; acc[3][2] += a3 * b2; acc[3][3] += a3 * b3;
        }
    }

#pragma unroll
    for (int i = 0; i < 4; i++) {
#pragma unroll
        for (int j = 0; j < 4; j++) {
            int m = row0 + ty * 4 + i;
            int n = tx * 4 + j;
            out[(long)h * M_ROWS * 64 + (long)m * 64 + n] = acc[i][j] + bias[h * 64 + n];
        }
    }
}

// ---------------------------------------------------------------------------
// Output GEMM: out[m][n] = sum_k A[m][k] * Wc[k][n] + bc[n]
// A: [M_ROWS, N_CAT=896], Wc: [896, 1024], out: [M_ROWS, 1024]
// grid: (M_ROWS/64, 1024/64), block: 256
// ---------------------------------------------------------------------------
__global__ __launch_bounds__(256)
void out_gemm(const float* __restrict__ A, const float* __restrict__ Wc,
              const float* __restrict__ bc, float* __restrict__ out)
{
    __shared__ float As[16][64];
    __shared__ float Bs[16][64];
    const int row0 = blockIdx.x * 64;
    const int col0 = blockIdx.y * 64;
    const int tid  = threadIdx.x;
    const int tx   = tid & 15;
    const int ty   = tid >> 4;

    const int am = tid >> 2;
    const int ak = (tid & 3) * 4;
    const int bk = tid >> 4;
    const int bn = (tid & 15) * 4;

    float acc[4][4] = {};

    for (int k0 = 0; k0 < N_CAT; k0 += 16) {
        float4 av = *(const float4*)&A[(long)(row0 + am) * N_CAT + k0 + ak];
        float4 bv = *(const float4*)&Wc[(long)(k0 + bk) * D_MODEL + col0 + bn];
        __syncthreads();
        As[ak + 0][am] = av.x; As[ak + 1][am] = av.y;
        As[ak + 2][am] = av.z; As[ak + 3][am] = av.w;
        *(float4*)&Bs[bk][bn] = bv;
        __syncthreads();
#pragma unroll
        for (int kk = 0; kk < 16; kk++) {
            float a0 = As[kk][ty * 4 + 0], a1 = As[kk][ty * 4 + 1];
            float a2 = As[kk][ty * 4 + 2], a3 = As[kk][ty * 4 + 3];
            float b0 = Bs[kk][tx * 4 + 0], b1 = Bs[kk][tx * 4 + 1];
            float b2 = Bs[kk][tx * 4 + 2], b3 = Bs[kk][tx * 4 + 3];
            acc[0][0] += a0 * b0; acc[0][1] += a0 * b1; acc[0][2] += a0 * b2; acc[0][3] += a0 * b3;
            acc[1][0] += a1 * b0; acc[1][1] += a1 * b1; acc[1][2] += a1 * b2; acc[1][3] += a1 * b3;
            acc[2][0] += a2 * b0; acc[2][1] += a2 * b1; acc[2][2] += a2 * b2; acc[2][3] += a2 * b3;
            acc[3][0] += a3 * b0; acc[3][1] += a3 * b1; acc[3][2] += a3 * b2; acc[3][3] += a3 * b3;
        }
    }

#pragma unroll
    for (int i = 0; i < 4; i++) {
#pragma unroll
        for (int j = 0; j < 4; j++) {
            int m = row0 + ty * 4 + i;
            int n = col0 + tx * 4 + j;
            out[(long)m * D_MODEL + n] = acc[i][j] + bc[n];
        }
    }
}

// ---------------------------------------------------------------------------
// Banded attention: one wave per (h, b, l) position.
// lane = Di index. Scores via full-wave shfl_xor reduction; Ws resample +
// softmax in lanes (m = lane&31, duplicated halves); PV via shfl broadcast.
// qb/kb: [S][M_ROWS][64], vb: [H][M_ROWS][64]
// ab (output): [M_ROWS][896] with col = h*64 + i  (concat layout for out_gemm)
// ---------------------------------------------------------------------------
__global__ __launch_bounds__(256)
void attn_kernel(const float* __restrict__ qb, const float* __restrict__ kb,
                 const float* __restrict__ vb, const float* __restrict__ Ws,
                 const float* __restrict__ bs, float* __restrict__ ab)
{
    const int wave = threadIdx.x >> 6;
    const int lane = threadIdx.x & 63;
    const long pos = (long)blockIdx.x * 4 + wave;   // h*8192 + b*4096 + l
    const int h  = (int)(pos >> 13);
    const int ml = (int)(pos & 8191);               // b*4096 + l
    const int l  = ml & 4095;
    const int sub = (h < 5) ? 0 : (h < 10) ? 1 : (h < 12) ? 2 : (h == 12) ? 3 : 4;
    const int dil = (sub <= 1) ? 1 : (1 << (sub - 1));   // 1,1,2,4,8

    const float qv = qb[((long)sub * M_ROWS + ml) * 64 + lane];
    const float* kbase = kb + ((long)sub * M_ROWS + (ml - l)) * 64;

    float sc[KW];
#pragma unroll
    for (int k = 0; k < KW; k++) {
        int src = l + (k - 16) * dil;
        src = src < 0 ? 0 : (src > L_SEQ - 1 ? L_SEQ - 1 : src);
        float p = qv * kbase[(long)src * 64 + lane];
#pragma unroll
        for (int off = 32; off > 0; off >>= 1) p += __shfl_xor(p, off, 64);
        sc[k] = p * 0.125f;   // / sqrt(64)
    }

    // positional resampling: lanes compute m = lane&31 (both halves identical)
    const int m = lane & 31;
    const float* wsrow = Ws + (long)h * KW * KW;
    float smp = bs[h * KW + m];
#pragma unroll
    for (int k = 0; k < KW; k++) smp += sc[k] * wsrow[k * KW + m];

    // softmax over 32 within each half-wave (xor masks 16..1 stay in-group)
    float mx = smp;
#pragma unroll
    for (int off = 16; off > 0; off >>= 1) mx = fmaxf(mx, __shfl_xor(mx, off, 64));
    float ex = __expf(smp - mx);
    float sum = ex;
#pragma unroll
    for (int off = 16; off > 0; off >>= 1) sum += __shfl_xor(sum, off, 64);
    const float attn = ex / sum;

    // PV: lane i accumulates over window positions; attn broadcast from lane m
    const float* vbase = vb + ((long)h * M_ROWS + (ml - l)) * 64;
    float o = 0.f;
#pragma unroll
    for (int mm = 0; mm < KW; mm++) {
        float am = __shfl(attn, mm, 64);
        int src = l + (mm - 16) * dil;
        src = src < 0 ? 0 : (src > L_SEQ - 1 ? L_SEQ - 1 : src);
        o += am * vbase[(long)src * 64 + lane];
    }

    ab[(long)ml * N_CAT + h * 64 + lane] = o;
}

// ---------------------------------------------------------------------------
extern "C" void kernel_launch(void* const* d_in, const int* in_sizes, int n_in,
                              void* d_out, int out_size, void* d_ws, size_t ws_size,
                              hipStream_t stream)
{
    const float* query = (const float*)d_in[0];
    const float* key   = (const float*)d_in[1];
    const float* value = (const float*)d_in[2];
    const float* Wq    = (const float*)d_in[3];
    const float* bq    = (const float*)d_in[4];
    const float* Wk    = (const float*)d_in[5];
    const float* bk    = (const float*)d_in[6];
    const float* Wv    = (const float*)d_in[7];
    const float* bv    = (const float*)d_in[8];
    const float* Ws    = (const float*)d_in[9];
    const float* bs    = (const float*)d_in[10];
    const float* Wc    = (const float*)d_in[11];
    const float* bc    = (const float*)d_in[12];
    float* out = (float*)d_out;

    float* ws = (float*)d_ws;
    float* qbuf = ws;                                     // 5*8192*64
    float* kbuf = qbuf + (long)SUBHEADS * M_ROWS * 64;    // 5*8192*64
    float* vbuf = kbuf + (long)SUBHEADS * M_ROWS * 64;    // 14*8192*64
    float* abuf = vbuf + (long)HEADS * M_ROWS * 64;       // 8192*896

    dim3 blk(256);
    proj_gemm<<<dim3(M_ROWS / 64, SUBHEADS), blk, 0, stream>>>(query, Wq, bq, qbuf);
    proj_gemm<<<dim3(M_ROWS / 64, SUBHEADS), blk, 0, stream>>>(key,   Wk, bk, kbuf);
    proj_gemm<<<dim3(M_ROWS / 64, HEADS),    blk, 0, stream>>>(value, Wv, bv, vbuf);

    const long npos = (long)HEADS * M_ROWS;               // 114688 waves
    attn_kernel<<<dim3((unsigned)(npos / 4)), blk, 0, stream>>>(qbuf, kbuf, vbuf, Ws, bs, abuf);

    out_gemm<<<dim3(M_ROWS / 64, D_MODEL / 64), blk, 0, stream>>>(abuf, Wc, bc, out);
}